// Round 6
// baseline (385.861 us; speedup 1.0000x reference)
//
#include <hip/hip_runtime.h>
#include <stdint.h>

// Problem constants
#define Bn 8
#define Tn 2048
#define Cn 1024
#define Mn (Bn * Tn)
#define NTRI 136   // causal 128x128 tiles per batch: 16*17/2

typedef __attribute__((ext_vector_type(4))) float f32x4;
typedef _Float16 f16;
typedef __attribute__((ext_vector_type(8))) _Float16 f16x8;
typedef uint16_t u16;
typedef uint32_t u32;

static __device__ __forceinline__ u16 f2h(float f) {
  union { f16 h; u16 u; } c; c.h = (f16)f; return c.u;
}
static __device__ __forceinline__ f32x4 mfmaH(f16x8 a, f16x8 b, f32x4 c) {
  return __builtin_amdgcn_mfma_f32_16x16x32_f16(a, b, c, 0, 0, 0);
}
// async global->LDS, 16B/lane; LDS dest = wave-uniform base + lane*16.
static __device__ __forceinline__ void gld16(const void* g, void* l) {
  __builtin_amdgcn_global_load_lds(
      (const __attribute__((address_space(1))) u32*)g,
      (__attribute__((address_space(3))) u32*)l, 16, 0, 0);
}

// ---------------------------------------------------------------------------
// ksplitW: W fp32 -> fp16 hi only.
// ---------------------------------------------------------------------------
__global__ __launch_bounds__(256) void ksplitW(const float* __restrict__ s,
                                               u16* __restrict__ hi) {
  size_t i = ((size_t)blockIdx.x * 256 + threadIdx.x) * 8;
  float4 a = *(const float4*)(s + i), b = *(const float4*)(s + i + 4);
  float f[8] = {a.x, a.y, a.z, a.w, b.x, b.y, b.z, b.w};
  union { u16 u[8]; uint4 v; } H;
#pragma unroll
  for (int j = 0; j < 8; ++j) H.u[j] = f2h(f[j]);
  *(uint4*)(hi + i) = H.v;
}

// ---------------------------------------------------------------------------
// ksplitX: x fp32 -> fp16 hi + fp16 lo residual (~22-bit effective).
// ---------------------------------------------------------------------------
__global__ __launch_bounds__(256) void ksplitX(const float* __restrict__ s,
                                               u16* __restrict__ hi,
                                               u16* __restrict__ lo) {
  size_t i = ((size_t)blockIdx.x * 256 + threadIdx.x) * 8;
  float4 a = *(const float4*)(s + i), b = *(const float4*)(s + i + 4);
  float f[8] = {a.x, a.y, a.z, a.w, b.x, b.y, b.z, b.w};
  union { u16 u[8]; uint4 v; } H, L;
#pragma unroll
  for (int j = 0; j < 8; ++j) {
    f16 h = (f16)f[j];
    union { f16 h; u16 u; } ch; ch.h = h;
    H.u[j] = ch.u;
    L.u[j] = f2h(f[j] - (float)h);
  }
  *(uint4*)(hi + i) = H.v;
  *(uint4*)(lo + i) = L.v;
}

// ---------------------------------------------------------------------------
// K1: xh = x_h @ W_h^T  (1 fp16 MFMA term). 128x128 tile, BK=64 as two
// [128][32] half-buffers (bank-identical to the proven BK=32 layout).
// ---------------------------------------------------------------------------
__global__ __launch_bounds__(256) void k1_xh(const u16* __restrict__ x_h,
                                             const u16* __restrict__ W_h,
                                             u16* __restrict__ xh) {
  __shared__ __align__(16) u16 Ah[8192], Bh[8192];
  const int tid = threadIdx.x;
  const int m0 = blockIdx.x * 128, n0 = blockIdx.y * 128;
  const int wave = tid >> 6, lane = tid & 63;
  const int wrow = (wave >> 1) * 64, wcol = (wave & 1) * 64;
  const int quad = lane >> 4, l16 = lane & 15;

  f32x4 acc[4][4] = {};

  for (int k0 = 0; k0 < Cn; k0 += 64) {
#pragma unroll
    for (int i = 0; i < 4; ++i) {
      int chunk = i * 256 + tid;
      int kk = chunk >> 9, row = (chunk >> 2) & 127, c8 = (chunk & 3) * 8;
      gld16(x_h + (size_t)(m0 + row) * Cn + k0 + kk * 32 + c8, Ah + chunk * 8);
      gld16(W_h + (size_t)(n0 + row) * Cn + k0 + kk * 32 + c8, Bh + chunk * 8);
    }
    __syncthreads();
#pragma unroll
    for (int kk = 0; kk < 2; ++kk) {
      f16x8 a[4], b[4];
#pragma unroll
      for (int i = 0; i < 4; ++i) {
        a[i] = *(const f16x8*)(Ah + kk * 4096 + (wrow + i * 16 + l16) * 32 + quad * 8);
        b[i] = *(const f16x8*)(Bh + kk * 4096 + (wcol + i * 16 + l16) * 32 + quad * 8);
      }
#pragma unroll
      for (int mi = 0; mi < 4; ++mi)
#pragma unroll
        for (int ni = 0; ni < 4; ++ni)
          acc[mi][ni] = mfmaH(a[mi], b[ni], acc[mi][ni]);
    }
    __syncthreads();
  }
#pragma unroll
  for (int mi = 0; mi < 4; ++mi)
#pragma unroll
    for (int ni = 0; ni < 4; ++ni)
#pragma unroll
      for (int r = 0; r < 4; ++r) {
        int row = wrow + mi * 16 + quad * 4 + r;
        int col = wcol + ni * 16 + l16;
        xh[(size_t)(m0 + row) * Cn + n0 + col] = f2h(acc[mi][ni][r]);
      }
}

// ---------------------------------------------------------------------------
// K2: S = (x_h + x_l) @ xh^T (2 terms); causal BM=128 x BN=256 tiles.
// R6 changes (both k2-internal):
// (a) 2-buffer depth-2 counted-vmcnt pipeline: stage(k+2) is issued AFTER
//     the bottom barrier into the buffer just computed (WAR-safe: all waves'
//     ds_reads of it completed before that barrier). vmcnt(4) at loop top
//     drains exactly the current buffer's 4 loads. LDS 96->64 KB -> 2
//     blocks/CU: all 288 blocks co-resident, kills the 2-round tail.
// (b) XCD-panel-affinity 1-D grid: xcd=bid%8 owns column-classes {p,7-p}
//     (p=xcd%4; sizes (16-2p)+(2p+2)=18/batch) x batch-half h=xcd/4 ->
//     exactly 36 blocks/XCD (nb=4) and each XCD's L2 retains its 4 xh
//     B-panels (4x512KB=2MB): same-panel blocks run concurrently on one
//     XCD and hit L2 instead of re-fetching (FETCH was 4.5x inputs).
// Accumulation order and epilogue unchanged -> output bit-identical.
// ---------------------------------------------------------------------------
__global__ __launch_bounds__(512) void k2_scores(const u16* __restrict__ x_h,
                                                 const u16* __restrict__ x_l,
                                                 const u16* __restrict__ xh,
                                                 u16* __restrict__ P,
                                                 float* __restrict__ mt,
                                                 float* __restrict__ lt) {
  __shared__ __align__(16) union {
    struct { u16 Ah[2][4096], Al[2][4096], Bh[2][8192]; } s;  // 64 KB
    struct { float Mrow[4][128]; float Lrow[4][128]; } e;     // overlays Ah[0]
  } u;
  const int tid = threadIdx.x;

  // ---- XCD-affinity decode: bid -> (bL, qt, bcol) ----
  const int bid = blockIdx.x;
  const int half = gridDim.x / 144;          // = nb/2 (grid.x = 72*nb)
  const int xcd = bid & 7, slot = bid >> 3;
  const int p = xcd & 3, h = xcd >> 2;
  const int n1 = 16 - 2 * p, n2 = 2 * p + 2;
  int c, j, bb;
  if (slot < n1 * half) {
    c = p; bb = slot / n1; j = slot % n1;
  } else {
    int s2 = slot - n1 * half; c = 7 - p; bb = s2 / n2; j = s2 % n2;
  }
  const int bL = h * half + bb;
  const int qt = 2 * c + j, bcol = c;
  const int t0 = qt * 128, s0 = bcol * 256;

  const int wave = tid >> 6, lane = tid & 63;
  const int wc = wave & 3;
  const int wrow = (wave >> 2) * 64, wcol = wc * 64;
  const int quad = lane >> 4, l16 = lane & 15;

  f32x4 acc[4][4] = {};
  const size_t abase = ((size_t)bL * Tn + t0) * Cn;
  const size_t bbase = ((size_t)bL * Tn + s0) * Cn;
  const int arow = tid >> 2, ac8 = (tid & 3) * 8;

  // 4 gld16 wave-instructions per stage -> steady-state wait is vmcnt(4).
  auto stage = [&](int buf, int k0) {
    size_t aoff = abase + (size_t)arow * Cn + k0 + ac8;
    gld16(x_h + aoff, &u.s.Ah[buf][tid * 8]);
    gld16(x_l + aoff, &u.s.Al[buf][tid * 8]);
#pragma unroll
    for (int i = 0; i < 2; ++i) {
      int ch = i * 512 + tid;
      int row = ch >> 2, c8 = (ch & 3) * 8;
      gld16(xh + bbase + (size_t)row * Cn + k0 + c8, &u.s.Bh[buf][ch * 8]);
    }
  };

  stage(0, 0);
  stage(1, 32);
#pragma unroll 1
  for (int kidx = 0; kidx < 32; ++kidx) {
    if (kidx < 31) {
      asm volatile("s_waitcnt vmcnt(4)" ::: "memory");
    } else {
      asm volatile("s_waitcnt vmcnt(0)" ::: "memory");
    }
    __builtin_amdgcn_s_barrier();
    __builtin_amdgcn_sched_barrier(0);
    const int cur = kidx & 1;
    f16x8 b[4];
#pragma unroll
    for (int ni = 0; ni < 4; ++ni)
      b[ni] = *(const f16x8*)&u.s.Bh[cur][(wcol + ni * 16 + l16) * 32 + quad * 8];
#pragma unroll
    for (int mi = 0; mi < 4; ++mi) {
      f16x8 ah = *(const f16x8*)&u.s.Ah[cur][(wrow + mi * 16 + l16) * 32 + quad * 8];
      f16x8 al = *(const f16x8*)&u.s.Al[cur][(wrow + mi * 16 + l16) * 32 + quad * 8];
#pragma unroll
      for (int ni = 0; ni < 4; ++ni) {
        acc[mi][ni] = mfmaH(ah, b[ni], acc[mi][ni]);
        acc[mi][ni] = mfmaH(al, b[ni], acc[mi][ni]);
      }
    }
    asm volatile("s_waitcnt lgkmcnt(0)" ::: "memory");
    __builtin_amdgcn_sched_barrier(0);
    __builtin_amdgcn_s_barrier();
    if (kidx < 30) stage(cur, (kidx + 2) * 32);
  }

  // ---- epilogue: mask, per-row max (per 128-half), exp, stats, packed-P ----
  // Mrow/Lrow overlay Ah[0] (first 4 KB); final iter (kidx=31) reads buf1
  // (offsets >= 8 KB) -> disjoint; __syncthreads below orders the reads.
  float rm[4][4];
#pragma unroll
  for (int mi = 0; mi < 4; ++mi)
#pragma unroll
    for (int r = 0; r < 4; ++r) {
      int row = wrow + mi * 16 + quad * 4 + r;
      float m = -1e30f;
#pragma unroll
      for (int ni = 0; ni < 4; ++ni) {
        int scol = s0 + wcol + ni * 16 + l16;
        if (scol >= t0 + row) acc[mi][ni][r] = -1e30f;
        m = fmaxf(m, acc[mi][ni][r]);
      }
      m = fmaxf(m, __shfl_xor(m, 1));
      m = fmaxf(m, __shfl_xor(m, 2));
      m = fmaxf(m, __shfl_xor(m, 4));
      m = fmaxf(m, __shfl_xor(m, 8));
      rm[mi][r] = m;
    }
  if (l16 == 0) {
#pragma unroll
    for (int mi = 0; mi < 4; ++mi)
#pragma unroll
      for (int r = 0; r < 4; ++r)
        u.e.Mrow[wc][wrow + mi * 16 + quad * 4 + r] = rm[mi][r];
  }
  __syncthreads();
  const int h2 = (wc >> 1) * 2;  // partner pair covering this 128-half
  float rs[4][4];
#pragma unroll
  for (int mi = 0; mi < 4; ++mi)
#pragma unroll
    for (int r = 0; r < 4; ++r) {
      int row = wrow + mi * 16 + quad * 4 + r;
      float m2 = fmaxf(u.e.Mrow[h2][row], u.e.Mrow[h2 + 1][row]);
      float s = 0.f;
#pragma unroll
      for (int ni = 0; ni < 4; ++ni) {
        int scol = s0 + wcol + ni * 16 + l16;
        float pv = (scol < t0 + row) ? __expf(acc[mi][ni][r] - m2) : 0.0f;
        acc[mi][ni][r] = pv;
        s += pv;
      }
      s += __shfl_xor(s, 1);
      s += __shfl_xor(s, 2);
      s += __shfl_xor(s, 4);
      s += __shfl_xor(s, 8);
      rs[mi][r] = s;
      rm[mi][r] = m2;
    }
  if (l16 == 0) {
#pragma unroll
    for (int mi = 0; mi < 4; ++mi)
#pragma unroll
      for (int r = 0; r < 4; ++r)
        u.e.Lrow[wc][wrow + mi * 16 + quad * 4 + r] = rs[mi][r];
  }
  __syncthreads();
  const int st128 = bcol * 2 + (wc >> 1);
  if (st128 <= qt) {  // even-qt diagonal rows have a dead right half-tile
    if ((wc & 1) == 0 && l16 == 0) {
#pragma unroll
      for (int mi = 0; mi < 4; ++mi)
#pragma unroll
        for (int r = 0; r < 4; ++r) {
          int row = wrow + mi * 16 + quad * 4 + r;
          size_t rI = (size_t)bL * Tn + t0 + row;
          mt[rI * 16 + st128] = rm[mi][r];
          lt[rI * 16 + st128] = u.e.Lrow[wc][row] + u.e.Lrow[wc + 1][row];
        }
    }
    const size_t pbase = (size_t)(bL * NTRI + qt * (qt + 1) / 2 + st128) * 16384;
#pragma unroll
    for (int mi = 0; mi < 4; ++mi)
#pragma unroll
      for (int ni = 0; ni < 4; ++ni)
#pragma unroll
        for (int r = 0; r < 4; ++r) {
          int row = wrow + mi * 16 + quad * 4 + r;
          int pcol = (wcol & 64) + ni * 16 + l16;
          P[pbase + row * 128 + pcol] = f2h(acc[mi][ni][r]);
        }
  }
}

// ---------------------------------------------------------------------------
// K3: per-row global max M and inverse denom Li. Row t=0 -> Li=0.
// ---------------------------------------------------------------------------
__global__ __launch_bounds__(256) void k3_stats(const float* __restrict__ mt,
                                                const float* __restrict__ lt,
                                                float* __restrict__ Mr,
                                                float* __restrict__ Li) {
  int r = blockIdx.x * 256 + threadIdx.x;
  int t = r & (Tn - 1);
  int nt = (t == 0) ? 0 : (((t - 1) >> 7) + 1);
  float M = -1e30f;
  for (int i = 0; i < nt; ++i) M = fmaxf(M, mt[(size_t)r * 16 + i]);
  float L = 0.f;
  for (int i = 0; i < nt; ++i) L += lt[(size_t)r * 16 + i] * __expf(mt[(size_t)r * 16 + i] - M);
  Mr[r] = M;
  Li[r] = (L > 0.f) ? 1.f / L : 0.f;
}

// ---------------------------------------------------------------------------
// ktr: xhT[b][c][s] = xh[b][s][c]  (fp16, 128x128 LDS tiles)
// ---------------------------------------------------------------------------
__global__ __launch_bounds__(256) void ktr(const u16* __restrict__ src,
                                           u16* __restrict__ dst) {
  __shared__ __align__(16) u16 S[128 * 136];
  const int t0 = blockIdx.x * 128, c0 = blockIdx.y * 128, b = blockIdx.z;
  const int tid = threadIdx.x;
#pragma unroll
  for (int i = 0; i < 8; ++i) {
    int chunk = tid + i * 256;
    int row = chunk >> 4, c8 = (chunk & 15) * 8;
    uint4 v = *(const uint4*)(src + ((size_t)b * Tn + t0 + row) * Cn + c0 + c8);
    *(uint4*)(S + row * 136 + c8) = v;
  }
  __syncthreads();
#pragma unroll
  for (int i = 0; i < 8; ++i) {
    int chunk = tid + i * 256;
    int crow = chunk >> 4, t8 = (chunk & 15) * 8;
    union { u16 s[8]; uint4 v; } o;
#pragma unroll
    for (int j = 0; j < 8; ++j) o.s[j] = S[(t8 + j) * 136 + crow];
    *(uint4*)(dst + ((size_t)b * Cn + c0 + crow) * Tn + t0 + t8) = o.v;
  }
}

// ---------------------------------------------------------------------------
// K4: out = -( (P*alpha) @ xh ), alpha folded into the A fragment.
// BM=128 x BN=256 + depth-2 counted-vmcnt pipeline (3 buffers, vmcnt(3)).
// alpha precomputed into a 4 KB LDS table. LDS 76 KB -> 2 blocks/CU.
// ---------------------------------------------------------------------------
__global__ __launch_bounds__(512) void k4_out(const u16* __restrict__ P,
                                              const u16* __restrict__ xhT,
                                              const float* __restrict__ mt,
                                              const float* __restrict__ Mr,
                                              const float* __restrict__ Li,
                                              float* __restrict__ out) {
  __shared__ __align__(16) u16 Ap[3][4096], Bp[3][8192];  // 72 KB
  __shared__ u16 alphaLds[16 * 128];                      // [st][row], 4 KB
  const int tid = threadIdx.x;
  const int tt = 15 - blockIdx.x;  // heavy tiles first
  const int cn = blockIdx.y, bL = blockIdx.z;
  const int t0 = tt * 128, c0 = cn * 256;
  const int wave = tid >> 6, lane = tid & 63;
  const int wc = wave & 3;
  const int wrow = (wave >> 2) * 64, wcol = wc * 64;
  const int quad = lane >> 4, l16 = lane & 15;

  // ---- prologue: alpha table (consumed before staging issues) ----
  {
    const size_t rbase = (size_t)bL * Tn + t0;
#pragma unroll
    for (int j = 0; j < 4; ++j) {
      int idx = tid + j * 512;
      int stp = idx >> 7, row = idx & 127;
      float a = 0.f;
      if (stp <= tt)
        a = __expf(mt[(rbase + row) * 16 + stp] - Mr[rbase + row]) * Li[rbase + row];
      alphaLds[idx] = f2h(a);
    }
  }

  f32x4 acc[4][4] = {};
  const size_t bbase = ((size_t)bL * Cn + c0) * Tn;
  const size_t ptile0 = (size_t)(bL * NTRI + tt * (tt + 1) / 2) * 16384;

  // 3 gld16 wave-instructions per stage -> steady-state wait is vmcnt(3).
  auto stage = [&](int buf, int step) {
    const int st = step >> 2, k32 = (step & 3) * 32;
    {
      int row = tid >> 2, c8 = (tid & 3) * 8;
      gld16(P + ptile0 + (size_t)st * 16384 + row * 128 + k32 + c8,
            &Ap[buf][tid * 8]);
    }
#pragma unroll
    for (int i = 0; i < 2; ++i) {
      int ch = i * 512 + tid;
      int row = ch >> 2, c8 = (ch & 3) * 8;
      gld16(xhT + bbase + (size_t)row * Tn + st * 128 + k32 + c8,
            &Bp[buf][ch * 8]);
    }
  };

  const int steps = 4 * (tt + 1);
  stage(0, 0);
  stage(1, 1);
  int cur = 0;
#pragma unroll 1
  for (int s = 0; s < steps; ++s) {
    if (s < steps - 1) {
      asm volatile("s_waitcnt vmcnt(3) lgkmcnt(0)" ::: "memory");
    } else {
      asm volatile("s_waitcnt vmcnt(0) lgkmcnt(0)" ::: "memory");
    }
    __builtin_amdgcn_s_barrier();
    __builtin_amdgcn_sched_barrier(0);
    if (s < steps - 2) {
      int tgt = cur >= 1 ? cur - 1 : 2;  // (s+2)%3
      stage(tgt, s + 2);
    }
    const int st = s >> 2;
    f16x8 b[4];
#pragma unroll
    for (int ni = 0; ni < 4; ++ni)
      b[ni] = *(const f16x8*)&Bp[cur][(wcol + ni * 16 + l16) * 32 + quad * 8];
#pragma unroll
    for (int mi = 0; mi < 4; ++mi) {
      union { u16 u; f16 h; } ca;
      ca.u = alphaLds[st * 128 + wrow + mi * 16 + l16];
      f16x8 sv;
#pragma unroll
      for (int j = 0; j < 8; ++j) sv[j] = ca.h;
      f16x8 a = *(const f16x8*)&Ap[cur][(wrow + mi * 16 + l16) * 32 + quad * 8];
      a = a * sv;
#pragma unroll
      for (int ni = 0; ni < 4; ++ni)
        acc[mi][ni] = mfmaH(a, b[ni], acc[mi][ni]);
    }
    cur = cur < 2 ? cur + 1 : 0;
  }

#pragma unroll
  for (int mi = 0; mi < 4; ++mi)
#pragma unroll
    for (int ni = 0; ni < 4; ++ni)
#pragma unroll
      for (int r = 0; r < 4; ++r) {
        int row = wrow + mi * 16 + quad * 4 + r;
        int col = wcol + ni * 16 + l16;
        out[((size_t)bL * Tn + t0 + row) * Cn + c0 + col] = -acc[mi][ni][r];
      }
}

// ---------------------------------------------------------------------------
extern "C" void kernel_launch(void* const* d_in, const int* in_sizes, int n_in,
                              void* d_out, int out_size, void* d_ws, size_t ws_size,
                              hipStream_t stream) {
  (void)in_sizes; (void)n_in; (void)out_size;
  const float* x = (const float*)d_in[0];
  const float* W = (const float*)d_in[1];
  float* out = (float*)d_out;

  // full-batch path needs ~140.6 MB; else fall back to 2 chunks (~71 MB)
  const size_t FULL_NEED = 3ull * Mn * Cn * 2 + (size_t)Bn * NTRI * 16384 * 2 +
                           (size_t)Cn * Cn * 2 + 2ull * Mn * 16 * 4 + 2ull * Mn * 4;
  const int nch = (ws_size >= FULL_NEED) ? 1 : 2;
  const int nb = Bn / nch;
  const size_t rowsC = (size_t)nb * Tn;       // rows per pass
  const size_t sA = rowsC * Cn * 2;           // fp16 plane bytes

  char* p = (char*)d_ws;
  u16* x_h = (u16*)p; p += sA;
  u16* xLT = (u16*)p; p += sA;                // x_l, later reused as xhT
  u16* xh  = (u16*)p; p += sA;
  u16* Pp  = (u16*)p; p += (size_t)nb * NTRI * 16384 * 2;
  u16* W_h = (u16*)p; p += (size_t)Cn * Cn * 2;
  float* mt = (float*)p; p += rowsC * 16 * 4;
  float* lt = (float*)p; p += rowsC * 16 * 4;
  float* Mr = (float*)p; p += rowsC * 4;
  float* Li = (float*)p; p += rowsC * 4;

  dim3 blk(256);
  ksplitW<<<dim3(Cn * Cn / 2048), blk, 0, stream>>>(W, W_h);
  for (int c = 0; c < nch; ++c) {
    const float* xc = x + (size_t)c * rowsC * Cn;
    float* oc = out + (size_t)c * rowsC * Cn;
    ksplitX<<<dim3((u32)(rowsC * Cn / 2048)), blk, 0, stream>>>(xc, x_h, xLT);
    k1_xh<<<dim3((u32)(rowsC / 128), Cn / 128), blk, 0, stream>>>(x_h, W_h, xh);
    k2_scores<<<dim3(72 * nb), dim3(512), 0, stream>>>(x_h, xLT, xh, Pp, mt, lt);
    k3_stats<<<dim3((u32)(rowsC / 256)), blk, 0, stream>>>(mt, lt, Mr, Li);
    ktr<<<dim3(Tn / 128, Cn / 128, nb), blk, 0, stream>>>(xh, xLT);
    k4_out<<<dim3(16, Cn / 256, nb), dim3(512), 0, stream>>>(Pp, xLT, mt, Mr, Li, oc);
  }
}

// Round 7
// 365.903 us; speedup vs baseline: 1.0545x; 1.0545x over previous
//
#include <hip/hip_runtime.h>
#include <stdint.h>

// Problem constants
#define Bn 8
#define Tn 2048
#define Cn 1024
#define Mn (Bn * Tn)
#define NTRI 136   // causal 128x128 tiles per batch: 16*17/2

typedef __attribute__((ext_vector_type(4))) float f32x4;
typedef _Float16 f16;
typedef __attribute__((ext_vector_type(8))) _Float16 f16x8;
typedef uint16_t u16;
typedef uint32_t u32;

static __device__ __forceinline__ u16 f2h(float f) {
  union { f16 h; u16 u; } c; c.h = (f16)f; return c.u;
}
static __device__ __forceinline__ f32x4 mfmaH(f16x8 a, f16x8 b, f32x4 c) {
  return __builtin_amdgcn_mfma_f32_16x16x32_f16(a, b, c, 0, 0, 0);
}
// async global->LDS, 16B/lane; LDS dest = wave-uniform base + lane*16.
static __device__ __forceinline__ void gld16(const void* g, void* l) {
  __builtin_amdgcn_global_load_lds(
      (const __attribute__((address_space(1))) u32*)g,
      (__attribute__((address_space(3))) u32*)l, 16, 0, 0);
}

// Bank-conflict swizzle (rule #21 compliant): LDS dest stays LINEAR for
// global_load_lds; the global SOURCE col is permuted per-lane by the
// involution q' = q ^ ((row>>1)&3) (same 64B segment -> coalescing intact),
// and LDS reads apply the same XOR. Spreads each half-wave's 16B requests
// over all 8 bank-granules (was 4 -> +8 cyc/read, SQ_LDS_BANK_CONFLICT
// = 8.0 per ds_read_b128 measured in R6).

// ---------------------------------------------------------------------------
// ksplitW: W fp32 -> fp16 hi only.
// ---------------------------------------------------------------------------
__global__ __launch_bounds__(256) void ksplitW(const float* __restrict__ s,
                                               u16* __restrict__ hi) {
  size_t i = ((size_t)blockIdx.x * 256 + threadIdx.x) * 8;
  float4 a = *(const float4*)(s + i), b = *(const float4*)(s + i + 4);
  float f[8] = {a.x, a.y, a.z, a.w, b.x, b.y, b.z, b.w};
  union { u16 u[8]; uint4 v; } H;
#pragma unroll
  for (int j = 0; j < 8; ++j) H.u[j] = f2h(f[j]);
  *(uint4*)(hi + i) = H.v;
}

// ---------------------------------------------------------------------------
// ksplitX: x fp32 -> fp16 hi + fp16 lo residual (~22-bit effective).
// ---------------------------------------------------------------------------
__global__ __launch_bounds__(256) void ksplitX(const float* __restrict__ s,
                                               u16* __restrict__ hi,
                                               u16* __restrict__ lo) {
  size_t i = ((size_t)blockIdx.x * 256 + threadIdx.x) * 8;
  float4 a = *(const float4*)(s + i), b = *(const float4*)(s + i + 4);
  float f[8] = {a.x, a.y, a.z, a.w, b.x, b.y, b.z, b.w};
  union { u16 u[8]; uint4 v; } H, L;
#pragma unroll
  for (int j = 0; j < 8; ++j) {
    f16 h = (f16)f[j];
    union { f16 h; u16 u; } ch; ch.h = h;
    H.u[j] = ch.u;
    L.u[j] = f2h(f[j] - (float)h);
  }
  *(uint4*)(hi + i) = H.v;
  *(uint4*)(lo + i) = L.v;
}

// ---------------------------------------------------------------------------
// K1: xh = x_h @ W_h^T  (1 fp16 MFMA term). 128x128 tile, BK=64 as two
// [128][32] half-buffers. Swizzled staging/reads (see header note).
// ---------------------------------------------------------------------------
__global__ __launch_bounds__(256) void k1_xh(const u16* __restrict__ x_h,
                                             const u16* __restrict__ W_h,
                                             u16* __restrict__ xh) {
  __shared__ __align__(16) u16 Ah[8192], Bh[8192];
  const int tid = threadIdx.x;
  const int m0 = blockIdx.x * 128, n0 = blockIdx.y * 128;
  const int wave = tid >> 6, lane = tid & 63;
  const int wrow = (wave >> 1) * 64, wcol = (wave & 1) * 64;
  const int quad = lane >> 4, l16 = lane & 15;
  const int ssw = ((((tid >> 3) & 3) ^ (tid & 3))) * 8;   // staging src col
  const int qs8 = (quad ^ ((l16 >> 1) & 3)) * 8;          // read col

  f32x4 acc[4][4] = {};

  for (int k0 = 0; k0 < Cn; k0 += 64) {
#pragma unroll
    for (int i = 0; i < 4; ++i) {
      int chunk = i * 256 + tid;
      int kk = chunk >> 9, row = (chunk >> 2) & 127;
      gld16(x_h + (size_t)(m0 + row) * Cn + k0 + kk * 32 + ssw, Ah + chunk * 8);
      gld16(W_h + (size_t)(n0 + row) * Cn + k0 + kk * 32 + ssw, Bh + chunk * 8);
    }
    __syncthreads();
#pragma unroll
    for (int kk = 0; kk < 2; ++kk) {
      f16x8 a[4], b[4];
#pragma unroll
      for (int i = 0; i < 4; ++i) {
        a[i] = *(const f16x8*)(Ah + kk * 4096 + (wrow + i * 16 + l16) * 32 + qs8);
        b[i] = *(const f16x8*)(Bh + kk * 4096 + (wcol + i * 16 + l16) * 32 + qs8);
      }
#pragma unroll
      for (int mi = 0; mi < 4; ++mi)
#pragma unroll
        for (int ni = 0; ni < 4; ++ni)
          acc[mi][ni] = mfmaH(a[mi], b[ni], acc[mi][ni]);
    }
    __syncthreads();
  }
#pragma unroll
  for (int mi = 0; mi < 4; ++mi)
#pragma unroll
    for (int ni = 0; ni < 4; ++ni)
#pragma unroll
      for (int r = 0; r < 4; ++r) {
        int row = wrow + mi * 16 + quad * 4 + r;
        int col = wcol + ni * 16 + l16;
        xh[(size_t)(m0 + row) * Cn + n0 + col] = f2h(acc[mi][ni][r]);
      }
}

// ---------------------------------------------------------------------------
// K2: S = (x_h + x_l) @ xh^T (2 terms); causal BM=128 x BN=256 tiles.
// R7 = R5's proven 3-buffer / 1-barrier / depth-2 counted-vmcnt loop
// (120 us) + R6's XCD-panel-affinity decode (FETCH 222->165 MB, free)
// + bank-conflict swizzle on staging source & LDS reads.
// ---------------------------------------------------------------------------
__global__ __launch_bounds__(512) void k2_scores(const u16* __restrict__ x_h,
                                                 const u16* __restrict__ x_l,
                                                 const u16* __restrict__ xh,
                                                 u16* __restrict__ P,
                                                 float* __restrict__ mt,
                                                 float* __restrict__ lt) {
  __shared__ __align__(16) union {
    struct { u16 Ah[3][4096], Al[3][4096], Bh[3][8192]; } s;  // 96 KB
    struct { float Mrow[4][128]; float Lrow[4][128]; } e;     // overlays Ah[0]
  } u;
  const int tid = threadIdx.x;

  // ---- XCD-affinity decode: bid -> (bL, qt, bcol) ----
  const int bid = blockIdx.x;
  const int half = gridDim.x / 144;          // = nb/2 (grid.x = 72*nb)
  const int xcd = bid & 7, slot = bid >> 3;
  const int p = xcd & 3, h = xcd >> 2;
  const int n1 = 16 - 2 * p, n2 = 2 * p + 2;
  int c, j, bb;
  if (slot < n1 * half) {
    c = p; bb = slot / n1; j = slot % n1;
  } else {
    int s2 = slot - n1 * half; c = 7 - p; bb = s2 / n2; j = s2 % n2;
  }
  const int bL = h * half + bb;
  const int qt = 2 * c + j, bcol = c;
  const int t0 = qt * 128, s0 = bcol * 256;

  const int wave = tid >> 6, lane = tid & 63;
  const int wc = wave & 3;
  const int wrow = (wave >> 2) * 64, wcol = wc * 64;
  const int quad = lane >> 4, l16 = lane & 15;
  const int ssw = ((((tid >> 3) & 3) ^ (tid & 3))) * 8;   // staging src col
  const int qs8 = (quad ^ ((l16 >> 1) & 3)) * 8;          // read col

  f32x4 acc[4][4] = {};
  const size_t abase = ((size_t)bL * Tn + t0) * Cn;
  const size_t bbase = ((size_t)bL * Tn + s0) * Cn;
  const int arow = tid >> 2;

  // 4 gld16 wave-instructions per stage -> steady-state wait is vmcnt(4).
  auto stage = [&](int buf, int k0) {
    size_t aoff = abase + (size_t)arow * Cn + k0 + ssw;
    gld16(x_h + aoff, &u.s.Ah[buf][tid * 8]);
    gld16(x_l + aoff, &u.s.Al[buf][tid * 8]);
#pragma unroll
    for (int i = 0; i < 2; ++i) {
      int ch = i * 512 + tid;
      int row = ch >> 2;
      gld16(xh + bbase + (size_t)row * Cn + k0 + ssw, &u.s.Bh[buf][ch * 8]);
    }
  };

  stage(0, 0);
  stage(1, 32);
  int cur = 0;
#pragma unroll 1
  for (int kidx = 0; kidx < 32; ++kidx) {
    if (kidx < 31) {
      asm volatile("s_waitcnt vmcnt(4) lgkmcnt(0)" ::: "memory");
    } else {
      asm volatile("s_waitcnt vmcnt(0) lgkmcnt(0)" ::: "memory");
    }
    __builtin_amdgcn_s_barrier();
    __builtin_amdgcn_sched_barrier(0);
    if (kidx < 30) {
      int tgt = cur >= 1 ? cur - 1 : 2;     // (kidx+2)%3
      stage(tgt, (kidx + 2) * 32);
    }
    f16x8 b[4];
#pragma unroll
    for (int ni = 0; ni < 4; ++ni)
      b[ni] = *(const f16x8*)&u.s.Bh[cur][(wcol + ni * 16 + l16) * 32 + qs8];
#pragma unroll
    for (int mi = 0; mi < 4; ++mi) {
      f16x8 ah = *(const f16x8*)&u.s.Ah[cur][(wrow + mi * 16 + l16) * 32 + qs8];
      f16x8 al = *(const f16x8*)&u.s.Al[cur][(wrow + mi * 16 + l16) * 32 + qs8];
#pragma unroll
      for (int ni = 0; ni < 4; ++ni) {
        acc[mi][ni] = mfmaH(ah, b[ni], acc[mi][ni]);
        acc[mi][ni] = mfmaH(al, b[ni], acc[mi][ni]);
      }
    }
    cur = cur < 2 ? cur + 1 : 0;
  }

  // ---- epilogue: mask, per-row max (per 128-half), exp, stats, packed-P ----
  float rm[4][4];
#pragma unroll
  for (int mi = 0; mi < 4; ++mi)
#pragma unroll
    for (int r = 0; r < 4; ++r) {
      int row = wrow + mi * 16 + quad * 4 + r;
      float m = -1e30f;
#pragma unroll
      for (int ni = 0; ni < 4; ++ni) {
        int scol = s0 + wcol + ni * 16 + l16;
        if (scol >= t0 + row) acc[mi][ni][r] = -1e30f;
        m = fmaxf(m, acc[mi][ni][r]);
      }
      m = fmaxf(m, __shfl_xor(m, 1));
      m = fmaxf(m, __shfl_xor(m, 2));
      m = fmaxf(m, __shfl_xor(m, 4));
      m = fmaxf(m, __shfl_xor(m, 8));
      rm[mi][r] = m;
    }
  if (l16 == 0) {
#pragma unroll
    for (int mi = 0; mi < 4; ++mi)
#pragma unroll
      for (int r = 0; r < 4; ++r)
        u.e.Mrow[wc][wrow + mi * 16 + quad * 4 + r] = rm[mi][r];
  }
  __syncthreads();
  const int h2 = (wc >> 1) * 2;  // partner pair covering this 128-half
  float rs[4][4];
#pragma unroll
  for (int mi = 0; mi < 4; ++mi)
#pragma unroll
    for (int r = 0; r < 4; ++r) {
      int row = wrow + mi * 16 + quad * 4 + r;
      float m2 = fmaxf(u.e.Mrow[h2][row], u.e.Mrow[h2 + 1][row]);
      float s = 0.f;
#pragma unroll
      for (int ni = 0; ni < 4; ++ni) {
        int scol = s0 + wcol + ni * 16 + l16;
        float pv = (scol < t0 + row) ? __expf(acc[mi][ni][r] - m2) : 0.0f;
        acc[mi][ni][r] = pv;
        s += pv;
      }
      s += __shfl_xor(s, 1);
      s += __shfl_xor(s, 2);
      s += __shfl_xor(s, 4);
      s += __shfl_xor(s, 8);
      rs[mi][r] = s;
      rm[mi][r] = m2;
    }
  if (l16 == 0) {
#pragma unroll
    for (int mi = 0; mi < 4; ++mi)
#pragma unroll
      for (int r = 0; r < 4; ++r)
        u.e.Lrow[wc][wrow + mi * 16 + quad * 4 + r] = rs[mi][r];
  }
  __syncthreads();
  const int st128 = bcol * 2 + (wc >> 1);
  if (st128 <= qt) {  // even-qt diagonal rows have a dead right half-tile
    if ((wc & 1) == 0 && l16 == 0) {
#pragma unroll
      for (int mi = 0; mi < 4; ++mi)
#pragma unroll
        for (int r = 0; r < 4; ++r) {
          int row = wrow + mi * 16 + quad * 4 + r;
          size_t rI = (size_t)bL * Tn + t0 + row;
          mt[rI * 16 + st128] = rm[mi][r];
          lt[rI * 16 + st128] = u.e.Lrow[wc][row] + u.e.Lrow[wc + 1][row];
        }
    }
    const size_t pbase = (size_t)(bL * NTRI + qt * (qt + 1) / 2 + st128) * 16384;
#pragma unroll
    for (int mi = 0; mi < 4; ++mi)
#pragma unroll
      for (int ni = 0; ni < 4; ++ni)
#pragma unroll
        for (int r = 0; r < 4; ++r) {
          int row = wrow + mi * 16 + quad * 4 + r;
          int pcol = (wcol & 64) + ni * 16 + l16;
          P[pbase + row * 128 + pcol] = f2h(acc[mi][ni][r]);
        }
  }
}

// ---------------------------------------------------------------------------
// K3: per-row global max M and inverse denom Li. Row t=0 -> Li=0.
// ---------------------------------------------------------------------------
__global__ __launch_bounds__(256) void k3_stats(const float* __restrict__ mt,
                                                const float* __restrict__ lt,
                                                float* __restrict__ Mr,
                                                float* __restrict__ Li) {
  int r = blockIdx.x * 256 + threadIdx.x;
  int t = r & (Tn - 1);
  int nt = (t == 0) ? 0 : (((t - 1) >> 7) + 1);
  float M = -1e30f;
  for (int i = 0; i < nt; ++i) M = fmaxf(M, mt[(size_t)r * 16 + i]);
  float L = 0.f;
  for (int i = 0; i < nt; ++i) L += lt[(size_t)r * 16 + i] * __expf(mt[(size_t)r * 16 + i] - M);
  Mr[r] = M;
  Li[r] = (L > 0.f) ? 1.f / L : 0.f;
}

// ---------------------------------------------------------------------------
// ktr: xhT[b][c][s] = xh[b][s][c]  (fp16, 128x128 LDS tiles)
// ---------------------------------------------------------------------------
__global__ __launch_bounds__(256) void ktr(const u16* __restrict__ src,
                                           u16* __restrict__ dst) {
  __shared__ __align__(16) u16 S[128 * 136];
  const int t0 = blockIdx.x * 128, c0 = blockIdx.y * 128, b = blockIdx.z;
  const int tid = threadIdx.x;
#pragma unroll
  for (int i = 0; i < 8; ++i) {
    int chunk = tid + i * 256;
    int row = chunk >> 4, c8 = (chunk & 15) * 8;
    uint4 v = *(const uint4*)(src + ((size_t)b * Tn + t0 + row) * Cn + c0 + c8);
    *(uint4*)(S + row * 136 + c8) = v;
  }
  __syncthreads();
#pragma unroll
  for (int i = 0; i < 8; ++i) {
    int chunk = tid + i * 256;
    int crow = chunk >> 4, t8 = (chunk & 15) * 8;
    union { u16 s[8]; uint4 v; } o;
#pragma unroll
    for (int j = 0; j < 8; ++j) o.s[j] = S[(t8 + j) * 136 + crow];
    *(uint4*)(dst + ((size_t)b * Cn + c0 + crow) * Tn + t0 + t8) = o.v;
  }
}

// ---------------------------------------------------------------------------
// K4: out = -( (P*alpha) @ xh ), alpha folded into the A fragment.
// BM=128 x BN=256 + depth-2 counted-vmcnt pipeline (3 buffers, vmcnt(3)).
// alpha precomputed into a 4 KB LDS table. + bank-conflict swizzle.
// ---------------------------------------------------------------------------
__global__ __launch_bounds__(512) void k4_out(const u16* __restrict__ P,
                                              const u16* __restrict__ xhT,
                                              const float* __restrict__ mt,
                                              const float* __restrict__ Mr,
                                              const float* __restrict__ Li,
                                              float* __restrict__ out) {
  __shared__ __align__(16) u16 Ap[3][4096], Bp[3][8192];  // 72 KB
  __shared__ u16 alphaLds[16 * 128];                      // [st][row], 4 KB
  const int tid = threadIdx.x;
  const int tt = 15 - blockIdx.x;  // heavy tiles first
  const int cn = blockIdx.y, bL = blockIdx.z;
  const int t0 = tt * 128, c0 = cn * 256;
  const int wave = tid >> 6, lane = tid & 63;
  const int wc = wave & 3;
  const int wrow = (wave >> 2) * 64, wcol = wc * 64;
  const int quad = lane >> 4, l16 = lane & 15;
  const int ssw = ((((tid >> 3) & 3) ^ (tid & 3))) * 8;   // staging src col
  const int qs8 = (quad ^ ((l16 >> 1) & 3)) * 8;          // read col

  // ---- prologue: alpha table (consumed before staging issues) ----
  {
    const size_t rbase = (size_t)bL * Tn + t0;
#pragma unroll
    for (int j = 0; j < 4; ++j) {
      int idx = tid + j * 512;
      int stp = idx >> 7, row = idx & 127;
      float a = 0.f;
      if (stp <= tt)
        a = __expf(mt[(rbase + row) * 16 + stp] - Mr[rbase + row]) * Li[rbase + row];
      alphaLds[idx] = f2h(a);
    }
  }

  f32x4 acc[4][4] = {};
  const size_t bbase = ((size_t)bL * Cn + c0) * Tn;
  const size_t ptile0 = (size_t)(bL * NTRI + tt * (tt + 1) / 2) * 16384;

  // 3 gld16 wave-instructions per stage -> steady-state wait is vmcnt(3).
  auto stage = [&](int buf, int step) {
    const int st = step >> 2, k32 = (step & 3) * 32;
    {
      int row = tid >> 2;
      gld16(P + ptile0 + (size_t)st * 16384 + row * 128 + k32 + ssw,
            &Ap[buf][tid * 8]);
    }
#pragma unroll
    for (int i = 0; i < 2; ++i) {
      int ch = i * 512 + tid;
      int row = ch >> 2;
      gld16(xhT + bbase + (size_t)row * Tn + st * 128 + k32 + ssw,
            &Bp[buf][ch * 8]);
    }
  };

  const int steps = 4 * (tt + 1);
  stage(0, 0);
  stage(1, 1);
  int cur = 0;
#pragma unroll 1
  for (int s = 0; s < steps; ++s) {
    if (s < steps - 1) {
      asm volatile("s_waitcnt vmcnt(3) lgkmcnt(0)" ::: "memory");
    } else {
      asm volatile("s_waitcnt vmcnt(0) lgkmcnt(0)" ::: "memory");
    }
    __builtin_amdgcn_s_barrier();
    __builtin_amdgcn_sched_barrier(0);
    if (s < steps - 2) {
      int tgt = cur >= 1 ? cur - 1 : 2;  // (s+2)%3
      stage(tgt, s + 2);
    }
    const int st = s >> 2;
    f16x8 b[4];
#pragma unroll
    for (int ni = 0; ni < 4; ++ni)
      b[ni] = *(const f16x8*)&Bp[cur][(wcol + ni * 16 + l16) * 32 + qs8];
#pragma unroll
    for (int mi = 0; mi < 4; ++mi) {
      union { u16 u; f16 h; } ca;
      ca.u = alphaLds[st * 128 + wrow + mi * 16 + l16];
      f16x8 sv;
#pragma unroll
      for (int j = 0; j < 8; ++j) sv[j] = ca.h;
      f16x8 a = *(const f16x8*)&Ap[cur][(wrow + mi * 16 + l16) * 32 + qs8];
      a = a * sv;
#pragma unroll
      for (int ni = 0; ni < 4; ++ni)
        acc[mi][ni] = mfmaH(a, b[ni], acc[mi][ni]);
    }
    cur = cur < 2 ? cur + 1 : 0;
  }

#pragma unroll
  for (int mi = 0; mi < 4; ++mi)
#pragma unroll
    for (int ni = 0; ni < 4; ++ni)
#pragma unroll
      for (int r = 0; r < 4; ++r) {
        int row = wrow + mi * 16 + quad * 4 + r;
        int col = wcol + ni * 16 + l16;
        out[((size_t)bL * Tn + t0 + row) * Cn + c0 + col] = -acc[mi][ni][r];
      }
}

// ---------------------------------------------------------------------------
extern "C" void kernel_launch(void* const* d_in, const int* in_sizes, int n_in,
                              void* d_out, int out_size, void* d_ws, size_t ws_size,
                              hipStream_t stream) {
  (void)in_sizes; (void)n_in; (void)out_size;
  const float* x = (const float*)d_in[0];
  const float* W = (const float*)d_in[1];
  float* out = (float*)d_out;

  // full-batch path needs ~140.6 MB; else fall back to 2 chunks (~71 MB)
  const size_t FULL_NEED = 3ull * Mn * Cn * 2 + (size_t)Bn * NTRI * 16384 * 2 +
                           (size_t)Cn * Cn * 2 + 2ull * Mn * 16 * 4 + 2ull * Mn * 4;
  const int nch = (ws_size >= FULL_NEED) ? 1 : 2;
  const int nb = Bn / nch;
  const size_t rowsC = (size_t)nb * Tn;       // rows per pass
  const size_t sA = rowsC * Cn * 2;           // fp16 plane bytes

  char* p = (char*)d_ws;
  u16* x_h = (u16*)p; p += sA;
  u16* xLT = (u16*)p; p += sA;                // x_l, later reused as xhT
  u16* xh  = (u16*)p; p += sA;
  u16* Pp  = (u16*)p; p += (size_t)nb * NTRI * 16384 * 2;
  u16* W_h = (u16*)p; p += (size_t)Cn * Cn * 2;
  float* mt = (float*)p; p += rowsC * 16 * 4;
  float* lt = (float*)p; p += rowsC * 16 * 4;
  float* Mr = (float*)p; p += rowsC * 4;
  float* Li = (float*)p; p += rowsC * 4;

  dim3 blk(256);
  ksplitW<<<dim3(Cn * Cn / 2048), blk, 0, stream>>>(W, W_h);
  for (int c = 0; c < nch; ++c) {
    const float* xc = x + (size_t)c * rowsC * Cn;
    float* oc = out + (size_t)c * rowsC * Cn;
    ksplitX<<<dim3((u32)(rowsC * Cn / 2048)), blk, 0, stream>>>(xc, x_h, xLT);
    k1_xh<<<dim3((u32)(rowsC / 128), Cn / 128), blk, 0, stream>>>(x_h, W_h, xh);
    k2_scores<<<dim3(72 * nb), dim3(512), 0, stream>>>(x_h, xLT, xh, Pp, mt, lt);
    k3_stats<<<dim3((u32)(rowsC / 256)), blk, 0, stream>>>(mt, lt, Mr, Li);
    ktr<<<dim3(Tn / 128, Cn / 128, nb), blk, 0, stream>>>(xh, xLT);
    k4_out<<<dim3(16, Cn / 256, nb), dim3(512), 0, stream>>>(Pp, xLT, mt, Mr, Li, oc);
  }
}